// Round 11
// baseline (318.522 us; speedup 1.0000x reference)
//
#include <hip/hip_runtime.h>
#include <hip/hip_bf16.h>
#include <math.h>

// NoisyTopkRouter: rows=32768, D=4096, E=64, k=8.
// R10: occupancy push. Double-buffered DMA (48KB LDS) + VGPR diet
// (__launch_bounds__(512,6), fi-serialized MFMA) -> target 3 blocks/CU,
// 6 waves/SIMD. fp16x2 split (3 MFMA/tile-step), W 2-plane image in d_ws.
// Output (fp32): gates[rows*64] | ix[rows*8] | full[rows*64]

typedef __attribute__((ext_vector_type(8))) _Float16 f16x8;
typedef __attribute__((ext_vector_type(4))) float f32x4;
typedef unsigned int u32;

#define BM 64
#define D_DIM 4096
#define NSTEP 128
#define WSTEP_BYTES 16384      // per-step W image: 2 planes x 8KB

// LDS: 2 buffers x (h 8KB + W 16KB) = 48KB
#define BUF_BYTES 24576
#define SMEM_BYTES 49152

__device__ __forceinline__ float softplus_f(float x) {
    return fmaxf(x, 0.0f) + log1pf(expf(-fabsf(x)));
}

__device__ __forceinline__ void gl16(void* lds, const void* g) {
    __builtin_amdgcn_global_load_lds(
        (const __attribute__((address_space(1))) u32*)g,
        (__attribute__((address_space(3))) u32*)lds, 16, 0, 0);
}

#define MFMA16F(A, B, C) __builtin_amdgcn_mfma_f32_16x16x32_f16((A), (B), (C), 0, 0, 0)

// ---- W pre-conversion: 2 fp16 planes (p0 = f16(w), p1 = f16((w-p0)*2048)),
// per-step 16KB fragment-ready image, chunk-swizzled: sc = c4 ^ ((vrow>>2)&3)
__global__ __launch_bounds__(256)
void wconv_kernel(const float* __restrict__ Ww, const float* __restrict__ Wn,
                  char* __restrict__ Wp)
{
    const int bid = blockIdx.x;            // 256 blocks
    const int kc = bid >> 1, half = bid & 1;
    const int t = threadIdx.x;
    const int vrow = half * 64 + (t >> 2); // 0..127 (0-63=Ww, 64-127=Wn)
    const int c4 = t & 3;                  // 16B chunk (8 fp32 k-elements -> 8 fp16)
    const float* src = (vrow < 64) ? (Ww + (size_t)vrow * D_DIM)
                                   : (Wn + (size_t)(vrow - 64) * D_DIM);
    const float4 a = *reinterpret_cast<const float4*>(src + kc * 32 + c4 * 8);
    const float4 b = *reinterpret_cast<const float4*>(src + kc * 32 + c4 * 8 + 4);
    const float f[8] = {a.x, a.y, a.z, a.w, b.x, b.y, b.z, b.w};
    union { _Float16 h[8]; uint4 q; } P0, P1;
#pragma unroll
    for (int i = 0; i < 8; ++i) {
        _Float16 lo = (_Float16)f[i];
        P0.h[i] = lo;
        P1.h[i] = (_Float16)((f[i] - (float)lo) * 2048.0f);
    }
    const int sc = c4 ^ ((vrow >> 2) & 3);
    char* dst = Wp + (size_t)kc * WSTEP_BYTES + vrow * 64 + sc * 16;
    *reinterpret_cast<uint4*>(dst)        = P0.q;
    *reinterpret_cast<uint4*>(dst + 8192) = P1.q;
}

__global__ __launch_bounds__(512, 6)
void router_kernel(const float* __restrict__ h,
                   const float* __restrict__ bw,
                   const float* __restrict__ bn,
                   const float* __restrict__ noise,
                   const char* __restrict__ Wp,
                   float* __restrict__ out_gates,
                   float* __restrict__ out_ix,
                   float* __restrict__ out_full)
{
    __shared__ __align__(16) char smem[SMEM_BYTES];

    const int t    = threadIdx.x;
    const int row0 = blockIdx.x * BM;
    const int lane = t & 63, w = t >> 6;        // 8 waves
    const int c = lane & 15, kg = lane >> 4;
    const int wr = w >> 2, wc = w & 3;          // 2x4 grid: rows wr*32.., vcols wc*32..

    // ---- staging geometry ----
    // h image[row*128 + sc*16] (raw fp32, sc = chunk ^ (row&7)): 1 gl16/thread
    const int hl  = lane >> 3;                  // row-within-8
    const int hsc = (lane & 7) ^ hl;            // pre-swizzled source chunk
    const float* hsrc = h + (size_t)(row0 + w * 8 + hl) * D_DIM + hsc * 4;
    const int hdst = w * 1024;                  // wave-uniform LDS base (+ lane*16 by DMA)
    const char* wsrc = Wp + w * 1024 + lane * 16;

    // ---- accumulators: grp (fold-16 main), sA, accM (@2^11) ----
    f32x4 grp[2][2], sA[2][2], accM[2][2];
#pragma unroll
    for (int fi = 0; fi < 2; ++fi)
#pragma unroll
        for (int j = 0; j < 2; ++j) {
            grp[fi][j] = (f32x4)0.0f; sA[fi][j] = (f32x4)0.0f;
            accM[fi][j] = (f32x4)0.0f;
        }

    // ---- prologue: stage step 0 into buf 0 ----
    gl16(smem + hdst, hsrc);
    gl16(smem + 8192 + w * 1024, wsrc);
    gl16(smem + 16384 + w * 1024, wsrc + 8192);
    asm volatile("s_waitcnt vmcnt(0)" ::: "memory");
    __builtin_amdgcn_sched_barrier(0);
    __builtin_amdgcn_s_barrier();
    __builtin_amdgcn_sched_barrier(0);

    for (int kc = 0; kc < NSTEP; ++kc) {
        // issue step kc+1 into the other buffer (freed at the last barrier);
        // it has this whole step's compute (~4500 cyc >> HBM latency) to land
        if (kc + 1 < NSTEP) {
            char* nb = smem + ((kc + 1) & 1) * BUF_BYTES;
            gl16(nb + hdst, hsrc + (size_t)(kc + 1) * 32);
            const char* ws = wsrc + (size_t)(kc + 1) * WSTEP_BYTES;
            gl16(nb + 8192 + w * 1024, ws);
            gl16(nb + 16384 + w * 1024, ws + 8192);
        }

        const char* hb = smem + (kc & 1) * BUF_BYTES;
        const char* wb = hb + 8192;

        // ---- fi-serialized: split A for one fi, use it, release ----
#pragma unroll
        for (int fi = 0; fi < 2; ++fi) {
            f16x8 A0f, A1f;
            {
                const int arow = wr * 32 + fi * 16 + c;
                const int s0 = ((kg * 2)     ^ (arow & 7)) * 16;
                const int s1 = ((kg * 2 + 1) ^ (arow & 7)) * 16;
                const float4 fa = *reinterpret_cast<const float4*>(hb + arow * 128 + s0);
                const float4 fb = *reinterpret_cast<const float4*>(hb + arow * 128 + s1);
                const float f[8] = {fa.x, fa.y, fa.z, fa.w, fb.x, fb.y, fb.z, fb.w};
#pragma unroll
                for (int i = 0; i < 8; ++i) {
                    _Float16 lo = (_Float16)f[i];
                    A0f[i] = lo;
                    A1f[i] = (_Float16)((f[i] - (float)lo) * 2048.0f);
                }
            }
#pragma unroll
            for (int j = 0; j < 2; ++j) {
                const int brow = wc * 32 + j * 16 + c;
                const int bo = brow * 64 + ((kg ^ ((brow >> 2) & 3)) * 16);
                const f16x8 B0 = *reinterpret_cast<const f16x8*>(wb + bo);
                const f16x8 B1 = *reinterpret_cast<const f16x8*>(wb + bo + 8192);
                grp[fi][j]  = MFMA16F(A0f, B0, grp[fi][j]);
                accM[fi][j] = MFMA16F(A0f, B1, accM[fi][j]);
                accM[fi][j] = MFMA16F(A1f, B0, accM[fi][j]);
            }
        }

        // fold group into sA every 16 steps (last fold at kc=127)
        if ((kc & 15) == 15) {
#pragma unroll
            for (int fi = 0; fi < 2; ++fi)
#pragma unroll
                for (int j = 0; j < 2; ++j) {
#pragma unroll
                    for (int e = 0; e < 4; ++e) sA[fi][j][e] += grp[fi][j][e];
                    grp[fi][j] = (f32x4)0.0f;
                }
        }

        // drain this step's issued loads (had full compute to land), rendezvous
        asm volatile("s_waitcnt vmcnt(0)" ::: "memory");
        __builtin_amdgcn_sched_barrier(0);
        __builtin_amdgcn_s_barrier();
        __builtin_amdgcn_sched_barrier(0);
    }

    // ---- logits -> LDS ----
    // C/D layout: col = lane&15, row = (lane>>4)*4 + reg
    float* lw_s = reinterpret_cast<float*>(smem);            // [64][65]
    float* ln_s = lw_s + 64 * 65;                            // [64][65]
    float* dst = (wc < 2) ? lw_s : ln_s;
#pragma unroll
    for (int fi = 0; fi < 2; ++fi)
#pragma unroll
        for (int j = 0; j < 2; ++j)
#pragma unroll
            for (int r = 0; r < 4; ++r) {
                const int rowl = wr * 32 + fi * 16 + kg * 4 + r;
                const int e = (wc & 1) * 32 + j * 16 + c;
                dst[rowl * 65 + e] = sA[fi][j][r] + accM[fi][j][r] * 4.8828125e-4f; // 2^-11
            }
    __syncthreads();

    // ---- noisy + top-8 + softmaxes: wave w -> rows w*8..w*8+7, lane = expert ----
    const float bwv = bw[lane];
    const float bnv = bn[lane];
    for (int q = 0; q < 8; ++q) {
        const int lrow = w * 8 + q;
        const int grow = row0 + lrow;
        const float lwv = lw_s[lrow * 65 + lane] + bwv;
        const float lnv = ln_s[lrow * 65 + lane] + bnv;
        const float nz  = noise[(size_t)grow * 64 + lane];
        const float v   = lwv + nz * softplus_f(lnv);

        float cur2 = v;
        float m8 = 0.0f;
        int winIdx = 0;
        bool picked = false;
#pragma unroll
        for (int r = 0; r < 8; ++r) {
            float bvv = cur2;
            int   bi  = lane;
#pragma unroll
            for (int off = 32; off; off >>= 1) {
                const float ov = __shfl_xor(bvv, off);
                const int   oi = __shfl_xor(bi, off);
                if (ov > bvv || (ov == bvv && oi < bi)) { bvv = ov; bi = oi; }
            }
            if (r == 0) m8 = bvv;
            if (lane == r) winIdx = bi;
            if (lane == bi) { picked = true; cur2 = -INFINITY; }
        }

        const float pf = expf(v - m8);
        const float pg = picked ? pf : 0.0f;
        float sf = pf, sg = pg;
#pragma unroll
        for (int off = 32; off; off >>= 1) {
            sf += __shfl_xor(sf, off);
            sg += __shfl_xor(sg, off);
        }

        out_full [(size_t)grow * 64 + lane] = pf / sf;
        out_gates[(size_t)grow * 64 + lane] = pg / sg;
        if (lane < 8) out_ix[(size_t)grow * 8 + lane] = (float)winIdx;
    }
}

extern "C" void kernel_launch(void* const* d_in, const int* in_sizes, int n_in,
                              void* d_out, int out_size, void* d_ws, size_t ws_size,
                              hipStream_t stream) {
    const float* h  = (const float*)d_in[0];
    const float* Ww = (const float*)d_in[1];
    const float* bw = (const float*)d_in[2];
    const float* Wn = (const float*)d_in[3];
    const float* bn = (const float*)d_in[4];
    const float* nz = (const float*)d_in[5];

    const int rows = in_sizes[5] / 64;   // 32768

    float* out = (float*)d_out;
    float* og = out;
    float* oi = out + (size_t)rows * 64;
    float* of = out + (size_t)rows * 64 + (size_t)rows * 8;

    char* Wp = (char*)d_ws;   // 128 steps * 16384 B = 2 MB

    hipLaunchKernelGGL(wconv_kernel, dim3(256), dim3(256), 0, stream, Ww, Wn, Wp);
    hipLaunchKernelGGL(router_kernel, dim3(rows / BM), dim3(512), 0, stream,
                       h, bw, bn, nz, Wp, og, oi, of);
}

// Round 12
// 243.472 us; speedup vs baseline: 1.3082x; 1.3082x over previous
//
#include <hip/hip_runtime.h>
#include <hip/hip_bf16.h>
#include <math.h>

// NoisyTopkRouter: rows=32768, D=4096, E=64, k=8.
// R12: 256-thr blocks (BM=32), 4 blocks/CU (4x40KB LDS), 1x4 wave grid.
// h reg-staged -> fp16x2 split ONCE -> LDS planes (XOR-swizzled b64);
// W 2-plane image DMA'd from d_ws. ONE barrier/step, counted vmcnt(5)
// keeps next step's 5 loads in flight across it. fp16x2 3-term MFMA, fold-16.
// Output (fp32): gates[rows*64] | ix[rows*8] | full[rows*64]

typedef __attribute__((ext_vector_type(8))) _Float16 f16x8;
typedef __attribute__((ext_vector_type(4))) float f32x4;
typedef unsigned int u32;

#define BM 32
#define D_DIM 4096
#define NSTEP 128
#define WSTEP_BYTES 16384   // per-step W image: 2 planes x 8KB

// per buffer: [W 16KB][hp0 2KB][hp1 2KB] = 20KB; 2 buffers = 40KB
#define BUF_BYTES 20480
#define SMEM_BYTES 40960

__device__ __forceinline__ float softplus_f(float x) {
    return fmaxf(x, 0.0f) + log1pf(expf(-fabsf(x)));
}

__device__ __forceinline__ void gl16(void* lds, const void* g) {
    __builtin_amdgcn_global_load_lds(
        (const __attribute__((address_space(1))) u32*)g,
        (__attribute__((address_space(3))) u32*)lds, 16, 0, 0);
}

#define MFMA16F(A, B, C) __builtin_amdgcn_mfma_f32_16x16x32_f16((A), (B), (C), 0, 0, 0)

// ---- W pre-conversion (unchanged from R8): 2 fp16 planes, per-step 16KB
// fragment-ready image, chunk-swizzled: sc = c4 ^ ((vrow>>2)&3)
__global__ __launch_bounds__(256)
void wconv_kernel(const float* __restrict__ Ww, const float* __restrict__ Wn,
                  char* __restrict__ Wp)
{
    const int bid = blockIdx.x;            // 256 blocks
    const int kc = bid >> 1, half = bid & 1;
    const int t = threadIdx.x;
    const int vrow = half * 64 + (t >> 2); // 0..127 (0-63=Ww, 64-127=Wn)
    const int c4 = t & 3;
    const float* src = (vrow < 64) ? (Ww + (size_t)vrow * D_DIM)
                                   : (Wn + (size_t)(vrow - 64) * D_DIM);
    const float4 a = *reinterpret_cast<const float4*>(src + kc * 32 + c4 * 8);
    const float4 b = *reinterpret_cast<const float4*>(src + kc * 32 + c4 * 8 + 4);
    const float f[8] = {a.x, a.y, a.z, a.w, b.x, b.y, b.z, b.w};
    union { _Float16 h[8]; uint4 q; } P0, P1;
#pragma unroll
    for (int i = 0; i < 8; ++i) {
        _Float16 lo = (_Float16)f[i];
        P0.h[i] = lo;
        P1.h[i] = (_Float16)((f[i] - (float)lo) * 2048.0f);
    }
    const int sc = c4 ^ ((vrow >> 2) & 3);
    char* dst = Wp + (size_t)kc * WSTEP_BYTES + vrow * 64 + sc * 16;
    *reinterpret_cast<uint4*>(dst)        = P0.q;
    *reinterpret_cast<uint4*>(dst + 8192) = P1.q;
}

__global__ __launch_bounds__(256, 4)
void router_kernel(const float* __restrict__ h,
                   const float* __restrict__ bw,
                   const float* __restrict__ bn,
                   const float* __restrict__ noise,
                   const char* __restrict__ Wp,
                   float* __restrict__ out_gates,
                   float* __restrict__ out_ix,
                   float* __restrict__ out_full)
{
    __shared__ __align__(16) char smem[SMEM_BYTES];

    const int t    = threadIdx.x;
    const int row0 = blockIdx.x * BM;          // 1024 blocks
    const int lane = t & 63, w = t >> 6;       // 4 waves, 1x4 grid (cols w*32)
    const int c = lane & 15, kg = lane >> 4;

    // ---- staging geometry ----
    // h: thread t -> row t>>3 (0..31), 16B chunk t&7; reg-staged then split
    const int hrow = t >> 3, hch = t & 7;
    const float* hsrc = h + (size_t)(row0 + hrow) * D_DIM + hch * 4;
    const int hwb = hrow * 64 + ((hch ^ (hrow & 7)) * 8);   // swizzled plane byte off
    // W: 4 gl16/thread, linear copy of the fragment-ready image
    const char* wsrc = Wp + w * 1024 + lane * 16;
    const int wdst = w * 1024;

    // ---- accumulators ----
    f32x4 grp[2][2], sA[2][2], accM[2][2];
#pragma unroll
    for (int fi = 0; fi < 2; ++fi)
#pragma unroll
        for (int j = 0; j < 2; ++j) {
            grp[fi][j] = (f32x4)0.0f; sA[fi][j] = (f32x4)0.0f;
            accM[fi][j] = (f32x4)0.0f;
        }

    float4 hvA, hvB;

    // ---- prologue ----
    hvA = *reinterpret_cast<const float4*>(hsrc);                 // h(0)  [vm]
#pragma unroll
    for (int i = 0; i < 4; ++i)                                   // WDMA(0) [vm x4]
        gl16(smem + wdst + i * 4096, wsrc + i * 4096);
    hvB = *reinterpret_cast<const float4*>(hsrc + 32);            // h(1)  [vm]
    asm volatile("s_waitcnt vmcnt(5)" ::: "memory");              // hvA ready
    __builtin_amdgcn_sched_barrier(0);
    {   // convert h(0) -> hplane[buf0]
        union { _Float16 q[4]; uint2 u; } L, H;
        const float f[4] = {hvA.x, hvA.y, hvA.z, hvA.w};
#pragma unroll
        for (int i = 0; i < 4; ++i) {
            _Float16 lo = (_Float16)f[i];
            L.q[i] = lo;
            H.q[i] = (_Float16)((f[i] - (float)lo) * 2048.0f);
        }
        *reinterpret_cast<uint2*>(smem + 16384 + hwb) = L.u;
        *reinterpret_cast<uint2*>(smem + 18432 + hwb) = H.u;
    }
    asm volatile("s_waitcnt lgkmcnt(0)" ::: "memory");
    __builtin_amdgcn_sched_barrier(0);
    __builtin_amdgcn_s_barrier();
    __builtin_amdgcn_sched_barrier(0);

    // ---- main loop: BODY(KC, ISS=reg filled for h(KC+2), CONV=reg holding h(KC+1)) ----
#define BODY(KC, ISS, CONV)                                                    \
    {                                                                          \
        if ((KC) + 2 < NSTEP)                                                  \
            ISS = *reinterpret_cast<const float4*>(hsrc + ((KC) + 2) * 32);    \
        if ((KC) + 1 < NSTEP) {                                                \
            char* nb = smem + (((KC) + 1) & 1) * BUF_BYTES;                    \
            const char* ws = wsrc + (size_t)((KC) + 1) * WSTEP_BYTES;          \
            _Pragma("unroll")                                                  \
            for (int i = 0; i < 4; ++i)                                        \
                gl16(nb + wdst + i * 4096, ws + i * 4096);                     \
        }                                                                      \
        if ((KC) + 2 < NSTEP)      asm volatile("s_waitcnt vmcnt(5)" ::: "memory"); \
        else if ((KC) + 1 < NSTEP) asm volatile("s_waitcnt vmcnt(4)" ::: "memory"); \
        else                       asm volatile("s_waitcnt vmcnt(0)" ::: "memory"); \
        __builtin_amdgcn_sched_barrier(0);                                     \
        if ((KC) + 1 < NSTEP) {   /* convert h(KC+1) -> hplanes of buf^1 */    \
            char* nb = smem + (((KC) + 1) & 1) * BUF_BYTES;                    \
            union { _Float16 q[4]; uint2 u; } L, H;                            \
            const float f[4] = {CONV.x, CONV.y, CONV.z, CONV.w};               \
            _Pragma("unroll")                                                  \
            for (int i = 0; i < 4; ++i) {                                      \
                _Float16 lo = (_Float16)f[i];                                  \
                L.q[i] = lo;                                                   \
                H.q[i] = (_Float16)((f[i] - (float)lo) * 2048.0f);             \
            }                                                                  \
            *reinterpret_cast<uint2*>(nb + 16384 + hwb) = L.u;                 \
            *reinterpret_cast<uint2*>(nb + 18432 + hwb) = H.u;                 \
        }                                                                      \
        const char* buf = smem + ((KC) & 1) * BUF_BYTES;                       \
        f16x8 A0[2], A1[2];                                                    \
        _Pragma("unroll")                                                      \
        for (int fi = 0; fi < 2; ++fi) {                                       \
            const int arow = fi * 16 + c;                                      \
            const int s0 = ((kg * 2)     ^ (arow & 7)) * 8;                    \
            const int s1 = ((kg * 2 + 1) ^ (arow & 7)) * 8;                    \
            union { uint2 d[2]; f16x8 v; } q0, q1;                             \
            q0.d[0] = *reinterpret_cast<const uint2*>(buf + 16384 + arow * 64 + s0); \
            q0.d[1] = *reinterpret_cast<const uint2*>(buf + 16384 + arow * 64 + s1); \
            q1.d[0] = *reinterpret_cast<const uint2*>(buf + 18432 + arow * 64 + s0); \
            q1.d[1] = *reinterpret_cast<const uint2*>(buf + 18432 + arow * 64 + s1); \
            A0[fi] = q0.v; A1[fi] = q1.v;                                      \
        }                                                                      \
        _Pragma("unroll")                                                      \
        for (int j = 0; j < 2; ++j) {                                          \
            const int brow = w * 32 + j * 16 + c;                              \
            const int bo = brow * 64 + ((kg ^ ((brow >> 2) & 3)) * 16);        \
            const f16x8 B0 = *reinterpret_cast<const f16x8*>(buf + bo);        \
            const f16x8 B1 = *reinterpret_cast<const f16x8*>(buf + bo + 8192); \
            _Pragma("unroll")                                                  \
            for (int fi = 0; fi < 2; ++fi) {                                   \
                grp[fi][j]  = MFMA16F(A0[fi], B0, grp[fi][j]);                 \
                accM[fi][j] = MFMA16F(A0[fi], B1, accM[fi][j]);                \
                accM[fi][j] = MFMA16F(A1[fi], B0, accM[fi][j]);                \
            }                                                                  \
        }                                                                      \
        if (((KC) & 15) == 15) {                                               \
            _Pragma("unroll")                                                  \
            for (int fi = 0; fi < 2; ++fi)                                     \
                _Pragma("unroll")                                              \
                for (int j = 0; j < 2; ++j) {                                  \
                    _Pragma("unroll")                                          \
                    for (int e = 0; e < 4; ++e) sA[fi][j][e] += grp[fi][j][e]; \
                    grp[fi][j] = (f32x4)0.0f;                                  \
                }                                                              \
        }                                                                      \
        asm volatile("s_waitcnt lgkmcnt(0)" ::: "memory");                     \
        __builtin_amdgcn_sched_barrier(0);                                     \
        __builtin_amdgcn_s_barrier();                                          \
        __builtin_amdgcn_sched_barrier(0);                                     \
    }

    for (int kc = 0; kc < NSTEP; kc += 2) {
        BODY(kc,     hvA, hvB);   // even: issue->hvA (h(kc+2)), convert hvB (h(kc+1))
        BODY(kc + 1, hvB, hvA);   // odd:  issue->hvB,           convert hvA
    }
#undef BODY

    // ---- logits -> LDS ----
    // C/D layout: col = lane&15, row = (lane>>4)*4 + reg
    float* lw_s = reinterpret_cast<float*>(smem);            // [32][65]
    float* ln_s = lw_s + 32 * 65;                            // [32][65]
    float* dst = (w < 2) ? lw_s : ln_s;
#pragma unroll
    for (int fi = 0; fi < 2; ++fi)
#pragma unroll
        for (int j = 0; j < 2; ++j)
#pragma unroll
            for (int r = 0; r < 4; ++r) {
                const int rowl = fi * 16 + kg * 4 + r;
                const int e = (w & 1) * 32 + j * 16 + c;
                dst[rowl * 65 + e] = sA[fi][j][r] + accM[fi][j][r] * 4.8828125e-4f; // 2^-11
            }
    __syncthreads();

    // ---- noisy + top-8 + softmaxes: wave w -> rows w*8..w*8+7, lane = expert ----
    const float bwv = bw[lane];
    const float bnv = bn[lane];
    for (int q = 0; q < 8; ++q) {
        const int lrow = w * 8 + q;
        const int grow = row0 + lrow;
        const float lwv = lw_s[lrow * 65 + lane] + bwv;
        const float lnv = ln_s[lrow * 65 + lane] + bnv;
        const float nz  = noise[(size_t)grow * 64 + lane];
        const float v   = lwv + nz * softplus_f(lnv);

        float cur2 = v;
        float m8 = 0.0f;
        int winIdx = 0;
        bool picked = false;
#pragma unroll
        for (int r = 0; r < 8; ++r) {
            float bvv = cur2;
            int   bi  = lane;
#pragma unroll
            for (int off = 32; off; off >>= 1) {
                const float ov = __shfl_xor(bvv, off);
                const int   oi = __shfl_xor(bi, off);
                if (ov > bvv || (ov == bvv && oi < bi)) { bvv = ov; bi = oi; }
            }
            if (r == 0) m8 = bvv;
            if (lane == r) winIdx = bi;
            if (lane == bi) { picked = true; cur2 = -INFINITY; }
        }

        const float pf = expf(v - m8);
        const float pg = picked ? pf : 0.0f;
        float sf = pf, sg = pg;
#pragma unroll
        for (int off = 32; off; off >>= 1) {
            sf += __shfl_xor(sf, off);
            sg += __shfl_xor(sg, off);
        }

        out_full [(size_t)grow * 64 + lane] = pf / sf;
        out_gates[(size_t)grow * 64 + lane] = pg / sg;
        if (lane < 8) out_ix[(size_t)grow * 8 + lane] = (float)winIdx;
    }
}

extern "C" void kernel_launch(void* const* d_in, const int* in_sizes, int n_in,
                              void* d_out, int out_size, void* d_ws, size_t ws_size,
                              hipStream_t stream) {
    const float* h  = (const float*)d_in[0];
    const float* Ww = (const float*)d_in[1];
    const float* bw = (const float*)d_in[2];
    const float* Wn = (const float*)d_in[3];
    const float* bn = (const float*)d_in[4];
    const float* nz = (const float*)d_in[5];

    const int rows = in_sizes[5] / 64;   // 32768

    float* out = (float*)d_out;
    float* og = out;
    float* oi = out + (size_t)rows * 64;
    float* of = out + (size_t)rows * 64 + (size_t)rows * 8;

    char* Wp = (char*)d_ws;   // 128 steps * 16384 B = 2 MB

    hipLaunchKernelGGL(wconv_kernel, dim3(256), dim3(256), 0, stream, Ww, Wn, Wp);
    hipLaunchKernelGGL(router_kernel, dim3(rows / BM), dim3(256), 0, stream,
                       h, bw, bn, nz, Wp, og, oi, of);
}